// Round 7
// baseline (256.362 us; speedup 1.0000x reference)
//
#include <hip/hip_runtime.h>
#include <hip/hip_bf16.h>

// ===================== Round 7: split-K + register prefetch =====================
// Locked: X fp32 [8192][3084]; out fp32 [8192][600]; W math verified (R4);
// MFMA frag layout + H1 epilogue verified (R4); cvt path verified (R4).
// R6 diagnosis: latency-bound, grid-limited occupancy (640 blocks = 2.5/CU,
// Occ 25%, Mfma 8.5%, VALU 9.7%, HBM 7%). Total-gemm gap ~107us is fixed
// harness overhead (unchanged across gen_W rewrite).
// Fix: split-K x2 (grid 1280 = 5 blocks/CU, fp32 atomicAdd epilogue + async
// memset of out) and software prefetch (next tile in regs during MFMA).

#define NFFT   512
#define HOP    128
#define KDIM   3084      // 257*6*2
#define KP     3104      // K padded (97*32)
#define NOUT   600
#define NP     640       // W rows padded (5*128)
#define BM     64
#define BN     128
#define BK     32
#define KSTEPS (KP / BK) // 97: split 49 + 48
#define LDA    40        // LDS row stride in shorts (32+8 pad) -> 80 B

typedef short s16x8 __attribute__((ext_vector_type(8)));
typedef float f32x4 __attribute__((ext_vector_type(4)));

static __device__ __forceinline__ unsigned short bf16_bits(float f) {
    __hip_bfloat16 b = __float2bfloat16(f);   // RNE - R4-verified path
    return *(unsigned short*)&b;
}

// ---------------- W generation: 1 block per row, cos-table in LDS -----------
__global__ __launch_bounds__(256) void gen_W(unsigned short* __restrict__ Wt) {
    __shared__ float costab[512];
    __shared__ __align__(16) unsigned short rowbuf[KP];   // 6208 B
    const int l   = blockIdx.x;     // 0..639
    const int tid = threadIdx.x;
    const float w0 = 6.283185307179586f / 512.0f;

    *(int4*)(rowbuf + tid * 8) = make_int4(0, 0, 0, 0);
    if (tid < 132) *(int4*)(rowbuf + (256 + tid) * 8) = make_int4(0, 0, 0, 0);
    costab[tid]       = __cosf((float)tid * w0);
    costab[tid + 256] = __cosf((float)(tid + 256) * w0);
    __syncthreads();

    if (l < NOUT) {
        const int p = l + 256;
        float env = 0.0f;
#pragma unroll
        for (int tt = 0; tt < 6; ++tt) {
            int m = p - HOP * tt;
            if (m >= 0 && m < NFFT) {
                float w = 0.5f - 0.5f * costab[m];
                env += w * w;
            }
        }
        const float inv = 1.0f / (512.0f * env);
        for (int f = tid; f <= 256; f += 256) {
            float cf = (f == 0 || f == 256) ? 1.0f : 2.0f;
#pragma unroll
            for (int t = 0; t < 6; ++t) {
                int n = p - HOP * t;
                if (n >= 0 && n < NFFT) {
                    float w = 0.5f - 0.5f * costab[n];
                    float scale = cf * w * inv;
                    int a = (f * n) & 511;
                    float c = costab[a];
                    float s = costab[(a + 384) & 511];
                    rowbuf[f * 12 + t * 2 + 0] = bf16_bits(scale * c);
                    rowbuf[f * 12 + t * 2 + 1] = bf16_bits(-scale * s);
                }
            }
        }
    }
    __syncthreads();

    unsigned short* dst = Wt + (size_t)l * KP;
    *(int4*)(dst + tid * 8) = *(const int4*)(rowbuf + tid * 8);
    if (tid < 132) *(int4*)(dst + (256 + tid) * 8) = *(const int4*)(rowbuf + (256 + tid) * 8);
}

// ---------------- GEMM: out += X * W^T (split-K halves) ----------------------
// BM=64, BN=128, BK=32; 256 thr = 4 waves, wave tile 32(m) x 64(n).
// Grid 1280 = 128 mt x 5 nt x 2 kidx.
__global__ __launch_bounds__(256, 5) void gemm_kernel(
        const float* __restrict__ X,           // fp32 [8192][3084]
        const unsigned short* __restrict__ Wt, // bf16 bits [640][3104]
        float* __restrict__ out) {             // fp32 [8192][600], pre-zeroed
    __shared__ __align__(16) unsigned short As[BM * LDA];  // 5.1 KB
    __shared__ __align__(16) unsigned short Bs[BN * LDA];  // 10.2 KB

    const int tid = threadIdx.x;
    // XCD swizzle: the 10 blocks (5 nt x 2 kidx) of one mt share an XCD.
    const int bid  = blockIdx.x;          // 0..1279
    const int xcd  = bid & 7;
    const int rest = bid >> 3;            // 0..159
    const int mt   = xcd * 16 + rest / 10;// 0..127
    const int sub  = rest % 10;
    const int nt   = sub >> 1;            // 0..4
    const int kidx = sub & 1;             // 0/1
    const int mBase = mt * BM;
    const int nBase = nt * BN;
    const int sBeg  = kidx ? 49 : 0;
    const int sEnd  = kidx ? KSTEPS : 49;

    const int lane = tid & 63;
    const int wave = tid >> 6;
    const int wm   = (wave & 1) * 32;
    const int wn   = (wave >> 1) * 64;
    const int lrow = lane & 15;
    const int quad = lane >> 4;
    const int koff = quad * 8;

    // staging indices (constant per thread)
    const int aRow0 = tid >> 3,  aU0 = tid & 7;          // pass 0
    const int aRow1 = (256 + tid) >> 3, aU1 = tid & 7;   // pass 1 (rows 32..63)
    const int bRow0 = tid >> 2,  bU0 = tid & 3;
    const int bRow1 = (256 + tid) >> 2, bU1 = tid & 3;

    f32x4 acc[2][4];
#pragma unroll
    for (int i = 0; i < 2; ++i)
#pragma unroll
        for (int j = 0; j < 4; ++j) acc[i][j] = (f32x4){0.f, 0.f, 0.f, 0.f};

    // ---- prologue: load first tile into registers
    float4 av[2];
    s16x8  bv[2];
    {
        const int k0 = sBeg * BK;
        int g0 = k0 + aU0 * 4;
        av[0] = make_float4(0.f, 0.f, 0.f, 0.f);
        av[1] = make_float4(0.f, 0.f, 0.f, 0.f);
        if (g0 < KDIM) {
            av[0] = *(const float4*)(X + (size_t)(mBase + aRow0) * KDIM + g0);
            av[1] = *(const float4*)(X + (size_t)(mBase + aRow1) * KDIM + g0);
        }
        bv[0] = *(const s16x8*)(const void*)(Wt + (size_t)(nBase + bRow0) * KP + k0 + bU0 * 8);
        bv[1] = *(const s16x8*)(const void*)(Wt + (size_t)(nBase + bRow1) * KP + k0 + bU1 * 8);
    }

    for (int step = sBeg; step < sEnd; ++step) {
        // ---- write staged registers to LDS
#pragma unroll
        for (int p = 0; p < 2; ++p) {
            float4 v = av[p];
            unsigned long long pk = (unsigned long long)bf16_bits(v.x) |
                                    ((unsigned long long)bf16_bits(v.y) << 16) |
                                    ((unsigned long long)bf16_bits(v.z) << 32) |
                                    ((unsigned long long)bf16_bits(v.w) << 48);
            int row = p ? aRow1 : aRow0;
            *(unsigned long long*)(As + row * LDA + aU0 * 4) = pk;
        }
        *(s16x8*)(void*)(Bs + bRow0 * LDA + bU0 * 8) = bv[0];
        *(s16x8*)(void*)(Bs + bRow1 * LDA + bU1 * 8) = bv[1];
        __syncthreads();

        // ---- prefetch next tile (overlaps with MFMA below)
        if (step + 1 < sEnd) {
            const int k0 = (step + 1) * BK;
            int g0 = k0 + aU0 * 4;
            av[0] = make_float4(0.f, 0.f, 0.f, 0.f);
            av[1] = make_float4(0.f, 0.f, 0.f, 0.f);
            if (g0 < KDIM) {
                av[0] = *(const float4*)(X + (size_t)(mBase + aRow0) * KDIM + g0);
                av[1] = *(const float4*)(X + (size_t)(mBase + aRow1) * KDIM + g0);
            }
            bv[0] = *(const s16x8*)(const void*)(Wt + (size_t)(nBase + bRow0) * KP + k0 + bU0 * 8);
            bv[1] = *(const s16x8*)(const void*)(Wt + (size_t)(nBase + bRow1) * KP + k0 + bU1 * 8);
        }

        // ---- compute current tile from LDS
        s16x8 bfr[4];
#pragma unroll
        for (int j = 0; j < 4; ++j)
            bfr[j] = *(const s16x8*)(const void*)(Bs + (wn + j * 16 + lrow) * LDA + koff);
#pragma unroll
        for (int i = 0; i < 2; ++i) {
            s16x8 afr = *(const s16x8*)(const void*)(As + (wm + i * 16 + lrow) * LDA + koff);
#pragma unroll
            for (int j = 0; j < 4; ++j)
                acc[i][j] = __builtin_amdgcn_mfma_f32_16x16x32_bf16(
                    afr, bfr[j], acc[i][j], 0, 0, 0);
        }
        __syncthreads();
    }

    // ---- epilogue: H1 layout (n=lane&15, m=quad*4+reg), atomic accumulate
#pragma unroll
    for (int i = 0; i < 2; ++i) {
#pragma unroll
        for (int j = 0; j < 4; ++j) {
            int gn = nBase + wn + j * 16 + lrow;
            if (gn < NOUT) {
#pragma unroll
                for (int r = 0; r < 4; ++r) {
                    int gm = mBase + wm + i * 16 + quad * 4 + r;
                    atomicAdd(out + (size_t)gm * NOUT + gn, acc[i][j][r]);
                }
            }
        }
    }
}

extern "C" void kernel_launch(void* const* d_in, const int* in_sizes, int n_in,
                              void* d_out, int out_size, void* d_ws, size_t ws_size,
                              hipStream_t stream) {
    const float* X = (const float*)d_in[0];
    unsigned short* W = (unsigned short*)d_ws;   // bf16 bits, 640*3104*2 = 3.97 MB
    float* out = (float*)d_out;

    hipMemsetAsync(d_out, 0, (size_t)out_size * sizeof(float), stream);
    gen_W<<<dim3(NP), 256, 0, stream>>>(W);
    gemm_kernel<<<dim3(128 * 5 * 2), 256, 0, stream>>>(X, W, out);
}

// Round 8
// 240.077 us; speedup vs baseline: 1.0678x; 1.0678x over previous
//
#include <hip/hip_runtime.h>
#include <hip/hip_bf16.h>

// ===================== Round 8: BK=64 — halve barrier drains =====================
// Locked: X fp32 [8192][3084]; out fp32 [8192][600]; W math + H1 epilogue +
// bf16-cvt path verified (R4). R7 post-mortem: occupancy 25->41% gave 0 gain;
// stall is the per-step __syncthreads vmcnt(0) drain (prefetch can't live
// across a barrier). Fix: BK 32->64 -> 49 steps instead of 97, 2x per-step
// MFMA window. Split-K=2 (grid 1280), fp32 atomicAdd epilogue, async memset.

#define NFFT   512
#define HOP    128
#define KDIM   3084      // 257*6*2
#define KP     3136      // K padded to 49*64
#define NOUT   600
#define NP     640       // W rows padded (5*128)
#define BM     64
#define BN     128
#define BK     64
#define KSTEPS (KP / BK) // 49: split 25 + 24
#define LDA    72        // LDS row stride in shorts (64+8) = 144 B; banks: 36 dw = 4 mod 32

typedef short s16x8 __attribute__((ext_vector_type(8)));
typedef float f32x4 __attribute__((ext_vector_type(4)));

static __device__ __forceinline__ unsigned short bf16_bits(float f) {
    __hip_bfloat16 b = __float2bfloat16(f);   // RNE - R4-verified path
    return *(unsigned short*)&b;
}

// ---------------- W generation: 1 block per row, cos-table in LDS -----------
__global__ __launch_bounds__(256) void gen_W(unsigned short* __restrict__ Wt) {
    __shared__ float costab[512];
    __shared__ __align__(16) unsigned short rowbuf[KP];   // 6272 B
    const int l   = blockIdx.x;     // 0..639
    const int tid = threadIdx.x;
    const float w0 = 6.283185307179586f / 512.0f;

    *(int4*)(rowbuf + tid * 8) = make_int4(0, 0, 0, 0);
    if (tid < 136) *(int4*)(rowbuf + (256 + tid) * 8) = make_int4(0, 0, 0, 0);
    costab[tid]       = __cosf((float)tid * w0);
    costab[tid + 256] = __cosf((float)(tid + 256) * w0);
    __syncthreads();

    if (l < NOUT) {
        const int p = l + 256;
        float env = 0.0f;
#pragma unroll
        for (int tt = 0; tt < 6; ++tt) {
            int m = p - HOP * tt;
            if (m >= 0 && m < NFFT) {
                float w = 0.5f - 0.5f * costab[m];
                env += w * w;
            }
        }
        const float inv = 1.0f / (512.0f * env);
        for (int f = tid; f <= 256; f += 256) {
            float cf = (f == 0 || f == 256) ? 1.0f : 2.0f;
#pragma unroll
            for (int t = 0; t < 6; ++t) {
                int n = p - HOP * t;
                if (n >= 0 && n < NFFT) {
                    float w = 0.5f - 0.5f * costab[n];
                    float scale = cf * w * inv;
                    int a = (f * n) & 511;
                    float c = costab[a];
                    float s = costab[(a + 384) & 511];
                    rowbuf[f * 12 + t * 2 + 0] = bf16_bits(scale * c);
                    rowbuf[f * 12 + t * 2 + 1] = bf16_bits(-scale * s);
                }
            }
        }
    }
    __syncthreads();

    unsigned short* dst = Wt + (size_t)l * KP;
    *(int4*)(dst + tid * 8) = *(const int4*)(rowbuf + tid * 8);
    if (tid < 136) *(int4*)(dst + (256 + tid) * 8) = *(const int4*)(rowbuf + (256 + tid) * 8);
}

// ---------------- GEMM: out += X * W^T (split-K halves, BK=64) ---------------
// 256 thr = 4 waves, wave tile 32(m) x 64(n); grid 1280 = 128mt x 5nt x 2k.
__global__ __launch_bounds__(256, 5) void gemm_kernel(
        const float* __restrict__ X,           // fp32 [8192][3084]
        const unsigned short* __restrict__ Wt, // bf16 bits [640][3136]
        float* __restrict__ out) {             // fp32 [8192][600], pre-zeroed
    __shared__ __align__(16) unsigned short As[BM * LDA];  // 9.2 KB
    __shared__ __align__(16) unsigned short Bs[BN * LDA];  // 18.4 KB

    const int tid = threadIdx.x;
    // XCD swizzle: the 10 blocks (5 nt x 2 kidx) of one mt share an XCD.
    const int bid  = blockIdx.x;           // 0..1279
    const int xcd  = bid & 7;
    const int rest = bid >> 3;             // 0..159
    const int mt   = xcd * 16 + rest / 10; // 0..127
    const int sub  = rest % 10;
    const int nt   = sub >> 1;             // 0..4
    const int kidx = sub & 1;              // 0/1
    const int mBase = mt * BM;
    const int nBase = nt * BN;
    const int sBeg  = kidx ? 25 : 0;
    const int sEnd  = kidx ? KSTEPS : 25;

    const int lane = tid & 63;
    const int wave = tid >> 6;
    const int wm   = (wave & 1) * 32;
    const int wn   = (wave >> 1) * 64;
    const int lrow = lane & 15;
    const int quad = lane >> 4;

    // staging maps (constant per thread):
    // A: 64 rows x 16 float4-cols; thread p-th unit: row = (tid>>4)+16p, col4 = tid&15
    // B: 128 rows x 8 s16x8-cols;  thread p-th unit: row = (tid>>3)+32p, col8 = tid&7
    const int aRow = tid >> 4, aU = tid & 15;
    const int bRow = tid >> 3, bU = tid & 7;
    const float* aPtr = X + (size_t)(mBase + aRow) * KDIM + sBeg * BK + aU * 4;
    const unsigned short* bPtr = Wt + (size_t)(nBase + bRow) * KP + sBeg * BK + bU * 8;
    const int aColBase = aU * 4;           // gcol = step*64 + aColBase (guard vs KDIM)
    const size_t aRowStride = (size_t)16 * KDIM;
    const size_t bRowStride = (size_t)32 * KP;

    f32x4 acc[2][4];
#pragma unroll
    for (int i = 0; i < 2; ++i)
#pragma unroll
        for (int j = 0; j < 4; ++j) acc[i][j] = (f32x4){0.f, 0.f, 0.f, 0.f};

    // ---- prologue: load first tile into registers
    float4 av[4];
    s16x8  bv[4];
    {
        const int k0 = sBeg * BK;
#pragma unroll
        for (int p = 0; p < 4; ++p) {
            av[p] = make_float4(0.f, 0.f, 0.f, 0.f);
            if (k0 + aColBase < KDIM) av[p] = *(const float4*)(aPtr + p * aRowStride);
            bv[p] = *(const s16x8*)(const void*)(bPtr + p * bRowStride);
        }
    }

    for (int step = sBeg; step < sEnd; ++step) {
        // ---- write staged registers to LDS
#pragma unroll
        for (int p = 0; p < 4; ++p) {
            float4 v = av[p];
            unsigned long long pk = (unsigned long long)bf16_bits(v.x) |
                                    ((unsigned long long)bf16_bits(v.y) << 16) |
                                    ((unsigned long long)bf16_bits(v.z) << 32) |
                                    ((unsigned long long)bf16_bits(v.w) << 48);
            *(unsigned long long*)(As + (aRow + 16 * p) * LDA + aU * 4) = pk;
            *(s16x8*)(void*)(Bs + (bRow + 32 * p) * LDA + bU * 8) = bv[p];
        }
        __syncthreads();

        // ---- prefetch next tile (hidden under the 16-MFMA window below)
        if (step + 1 < sEnd) {
            const int k0 = (step + 1) * BK;
#pragma unroll
            for (int p = 0; p < 4; ++p) {
                av[p] = make_float4(0.f, 0.f, 0.f, 0.f);
                if (k0 + aColBase < KDIM)
                    av[p] = *(const float4*)(aPtr + (size_t)(step + 1 - sBeg) * BK + p * aRowStride);
                bv[p] = *(const s16x8*)(const void*)(bPtr + (size_t)(step + 1 - sBeg) * BK + p * bRowStride);
            }
        }

        // ---- compute current tile from LDS (2 k-subtiles of 32)
#pragma unroll
        for (int ks = 0; ks < 2; ++ks) {
            const int koff = ks * 32 + quad * 8;
            s16x8 bfr[4];
#pragma unroll
            for (int j = 0; j < 4; ++j)
                bfr[j] = *(const s16x8*)(const void*)(Bs + (wn + j * 16 + lrow) * LDA + koff);
#pragma unroll
            for (int i = 0; i < 2; ++i) {
                s16x8 afr = *(const s16x8*)(const void*)(As + (wm + i * 16 + lrow) * LDA + koff);
#pragma unroll
                for (int j = 0; j < 4; ++j)
                    acc[i][j] = __builtin_amdgcn_mfma_f32_16x16x32_bf16(
                        afr, bfr[j], acc[i][j], 0, 0, 0);
            }
        }
        __syncthreads();
    }

    // ---- epilogue: H1 layout (n=lane&15, m=quad*4+reg), atomic accumulate
#pragma unroll
    for (int i = 0; i < 2; ++i) {
#pragma unroll
        for (int j = 0; j < 4; ++j) {
            int gn = nBase + wn + j * 16 + lrow;
            if (gn < NOUT) {
#pragma unroll
                for (int r = 0; r < 4; ++r) {
                    int gm = mBase + wm + i * 16 + quad * 4 + r;
                    atomicAdd(out + (size_t)gm * NOUT + gn, acc[i][j][r]);
                }
            }
        }
    }
}

extern "C" void kernel_launch(void* const* d_in, const int* in_sizes, int n_in,
                              void* d_out, int out_size, void* d_ws, size_t ws_size,
                              hipStream_t stream) {
    const float* X = (const float*)d_in[0];
    unsigned short* W = (unsigned short*)d_ws;   // bf16 bits, 640*3136*2 = 4.01 MB
    float* out = (float*)d_out;

    hipMemsetAsync(d_out, 0, (size_t)out_size * sizeof(float), stream);
    gen_W<<<dim3(NP), 256, 0, stream>>>(W);
    gemm_kernel<<<dim3(128 * 5 * 2), 256, 0, stream>>>(X, W, out);
}